// Round 20
// baseline (110.959 us; speedup 1.0000x reference)
//
#include <hip/hip_runtime.h>
#include <hip/hip_bf16.h>

typedef __attribute__((ext_vector_type(8))) short bf16x8;
typedef __attribute__((ext_vector_type(4))) float f32x4;

__device__ __forceinline__ ushort f2bf(float f) {
    __hip_bfloat16 h = __float2bfloat16(f);
    return __builtin_bit_cast(ushort, h);
}
__device__ __forceinline__ unsigned pack2(float a, float b) {
    return (unsigned)f2bf(a) | ((unsigned)f2bf(b) << 16);
}
__device__ __forceinline__ float bflo(unsigned u) { return __uint_as_float(u << 16); }
__device__ __forceinline__ float bfhi(unsigned u) { return __uint_as_float(u & 0xffff0000u); }

__device__ __forceinline__ void unpack8(uint4 r, float* o) {
    o[0] = bflo(r.x); o[1] = bfhi(r.x); o[2] = bflo(r.y); o[3] = bfhi(r.y);
    o[4] = bflo(r.z); o[5] = bfhi(r.z); o[6] = bflo(r.w); o[7] = bfhi(r.w);
}
__device__ __forceinline__ bf16x8 cvt8(float4 u0, float4 u1) {
    uint4 p;
    p.x = pack2(u0.x, u0.y); p.y = pack2(u0.z, u0.w);
    p.z = pack2(u1.x, u1.y); p.w = pack2(u1.z, u1.w);
    return __builtin_bit_cast(bf16x8, p);
}

// ---------------------------------------------------------------------------
// L1: kv16 = bf16(w_kv @ cond + b_kv). BM=128, BN=32, BK=64, K=512.
// A-fragments loaded DIRECTLY from L2 (w_kv is 512 KB, cached) — no A LDS.
// 256 thr (4 waves), 12 KB LDS. grid (32 nc, 2 rb, 16 b).
// First 264 flat-blocks also zero rowsum+ctx.
__global__ __launch_bounds__(256) void kv_gemm(const float* __restrict__ w_kv,
                                               const float* __restrict__ cond,
                                               const float* __restrict__ b_kv,
                                               ushort* __restrict__ kv16,
                                               float* __restrict__ zbase) {
    __shared__ ushort lB[32 * 64];      // 4 KB
    __shared__ float scratch[64 * 32];  // 8 KB, granule-swizzled
    int nc = blockIdx.x, rb = blockIdx.y, b = blockIdx.z;
    int t = threadIdx.x;
    int fid = blockIdx.x + 32 * (blockIdx.y + 2 * blockIdx.z);
    if (fid < 264) zbase[fid * 256 + t] = 0.f;   // rowsum(2048)+ctx(65536)
    int col0 = nc * 32, row0 = rb * 128;
    int l = t & 63, w = t >> 6;          // 4 waves, rows w*32..w*32+31
    int lr = l & 15, lg = l >> 4;
    const float* Bb = cond + (size_t)b * 512 * 1024 + col0;
    const float* Ar0 = w_kv + (size_t)(row0 + w * 32 + lr) * 512;       // mi=0 row
    const float* Ar1 = w_kv + (size_t)(row0 + w * 32 + 16 + lr) * 512;  // mi=1 row
    int kq0 = lg * 8, kq1 = (4 + lg) * 8;   // ks=0 / ks=1 k-offsets
    int rB = t >> 3, gB = t & 7;         // rows rB, 32+rB; granule gB of 8
    int sp = t & 31, sj4 = (t >> 5) & 7; // pack: rows 2sp,2sp+1; n-quad sj4
    float4 kb0_, kb1_;
    bf16x8 af00_, af01_, af10_, af11_;   // A frags [mi][ks]
#define KG_LOADB(k0) { \
    kb0_ = *(const float4*)&Bb[(size_t)((k0) + rB)      * 1024 + gB * 4]; \
    kb1_ = *(const float4*)&Bb[(size_t)((k0) + 32 + rB) * 1024 + gB * 4]; }
#define KG_LOADAF(k0) { \
    af00_ = cvt8(*(const float4*)&Ar0[(k0) + kq0], *(const float4*)&Ar0[(k0) + kq0 + 4]); \
    af01_ = cvt8(*(const float4*)&Ar0[(k0) + kq1], *(const float4*)&Ar0[(k0) + kq1 + 4]); \
    af10_ = cvt8(*(const float4*)&Ar1[(k0) + kq0], *(const float4*)&Ar1[(k0) + kq0 + 4]); \
    af11_ = cvt8(*(const float4*)&Ar1[(k0) + kq1], *(const float4*)&Ar1[(k0) + kq1 + 4]); }
#define KG_WRITEB() { \
    *(float4*)((char*)scratch + (rB)      * 128 + ((gB ^ (((rB)      >> 1) & 7)) * 16)) = kb0_; \
    *(float4*)((char*)scratch + (32 + rB) * 128 + ((gB ^ (((32 + rB) >> 1) & 7)) * 16)) = kb1_; }
#define KG_PACKB() { \
    int js = sj4 ^ (sp & 7); \
    float4 s0 = *(const float4*)((char*)scratch + (2*sp)   * 128 + js * 16); \
    float4 s2 = *(const float4*)((char*)scratch + (2*sp+1) * 128 + js * 16); \
    float c0v[4] = {s0.x, s0.y, s0.z, s0.w}; \
    float c1v[4] = {s2.x, s2.y, s2.z, s2.w}; \
    _Pragma("unroll") \
    for (int w4 = 0; w4 < 4; ++w4) { \
        int n = sj4 * 4 + w4; \
        unsigned pk = pack2(c0v[w4], c1v[w4]); \
        *(unsigned*)((char*)lB + n * 128 + (((sp >> 2) ^ (n & 7)) * 16) + (sp & 3) * 4) = pk; \
    } }
    KG_LOADB(0);
    f32x4 acc00 = {}, acc01 = {}, acc10 = {}, acc11 = {};
    for (int it = 0; it < 8; ++it) {
        int k0 = it * 64;
        KG_WRITEB();
        __syncthreads();
        if (it < 7) KG_LOADB(k0 + 64);      // B prefetch
        KG_LOADAF(k0);                       // A frags direct from L2
        KG_PACKB();
        __syncthreads();
        __builtin_amdgcn_s_setprio(1);
        {   // ks = 0
            int br0 = lr,      q0 = lg ^ (br0 & 7);
            int br1 = 16 + lr, q1 = lg ^ (br1 & 7);
            bf16x8 bv0 = *(const bf16x8*)((const char*)lB + br0 * 128 + q0 * 16);
            bf16x8 bv1 = *(const bf16x8*)((const char*)lB + br1 * 128 + q1 * 16);
            acc00 = __builtin_amdgcn_mfma_f32_16x16x32_bf16(af00_, bv0, acc00, 0, 0, 0);
            acc01 = __builtin_amdgcn_mfma_f32_16x16x32_bf16(af00_, bv1, acc01, 0, 0, 0);
            acc10 = __builtin_amdgcn_mfma_f32_16x16x32_bf16(af10_, bv0, acc10, 0, 0, 0);
            acc11 = __builtin_amdgcn_mfma_f32_16x16x32_bf16(af10_, bv1, acc11, 0, 0, 0);
        }
        {   // ks = 1
            int br0 = lr,      q0 = (4 + lg) ^ (br0 & 7);
            int br1 = 16 + lr, q1 = (4 + lg) ^ (br1 & 7);
            bf16x8 bv0 = *(const bf16x8*)((const char*)lB + br0 * 128 + q0 * 16);
            bf16x8 bv1 = *(const bf16x8*)((const char*)lB + br1 * 128 + q1 * 16);
            acc00 = __builtin_amdgcn_mfma_f32_16x16x32_bf16(af01_, bv0, acc00, 0, 0, 0);
            acc01 = __builtin_amdgcn_mfma_f32_16x16x32_bf16(af01_, bv1, acc01, 0, 0, 0);
            acc10 = __builtin_amdgcn_mfma_f32_16x16x32_bf16(af11_, bv0, acc10, 0, 0, 0);
            acc11 = __builtin_amdgcn_mfma_f32_16x16x32_bf16(af11_, bv1, acc11, 0, 0, 0);
        }
        __builtin_amdgcn_s_setprio(0);
        __syncthreads();
    }
#undef KG_LOADB
#undef KG_LOADAF
#undef KG_WRITEB
#undef KG_PACKB
    int orow = row0 + w * 32;
    #pragma unroll
    for (int mi = 0; mi < 2; ++mi) {
        int rbase = orow + mi * 16 + lg * 4;
        float4 b4 = *(const float4*)&b_kv[rbase];
        float bvr[4] = {b4.x, b4.y, b4.z, b4.w};
        f32x4 a0 = mi == 0 ? acc00 : acc10;
        f32x4 a1 = mi == 0 ? acc01 : acc11;
        #pragma unroll
        for (int r = 0; r < 4; ++r) {
            kv16[((size_t)b * 256 + rbase + r) * 1024 + col0 + lr]      = f2bf(a0[r] + bvr[r]);
            kv16[((size_t)b * 256 + rbase + r) * 1024 + col0 + 16 + lr] = f2bf(a1[r] + bvr[r]);
        }
    }
}

// ---------------------------------------------------------------------------
// L2 mixed: bid<512: partial context (UNNORMALIZED, atomics):
//   ctx[d,e] += sum_n exp(k[d,n]) v[e,n], rowsum[d] += sum_n exp(k[d,n]).
//   bid>=512: GroupNorm sums for x, one block per (b,g), plain store.
__global__ __launch_bounds__(256) void ctxstats_kernel(const ushort* __restrict__ kv,
                                                       const float* __restrict__ x,
                                                       float* __restrict__ rowsum,
                                                       float* __restrict__ ctx,
                                                       float* __restrict__ statacc) {
    __shared__ float pl[32][129], vl[32][129];
    int bid = blockIdx.x, t = threadIdx.x;
    if (bid < 512) {
        int bh = bid >> 3, b = bh >> 2, h = bh & 3;
        int n0 = (bid & 7) * 128;
        int r = t >> 3, cs = (t & 7) * 16;
        const ushort* kp = kv + ((size_t)b * 256 + h * 32 + r) * 1024 + n0 + cs;
        const ushort* vp = kv + ((size_t)b * 256 + 128 + h * 32 + r) * 1024 + n0 + cs;
        float kvals[16], vvals[16];
        unpack8(((const uint4*)kp)[0], kvals);
        unpack8(((const uint4*)kp)[1], kvals + 8);
        unpack8(((const uint4*)vp)[0], vvals);
        unpack8(((const uint4*)vp)[1], vvals + 8);
        float psum = 0.f;
        #pragma unroll
        for (int i = 0; i < 16; ++i) {
            float e = __expf(kvals[i]);
            pl[r][cs + i] = e;
            vl[r][cs + i] = vvals[i];
            psum += e;
        }
        psum += __shfl_xor(psum, 1, 64);
        psum += __shfl_xor(psum, 2, 64);
        psum += __shfl_xor(psum, 4, 64);
        if ((t & 7) == 0) atomicAdd(&rowsum[bh * 32 + r], psum);
        __syncthreads();
        int d0 = t >> 5, e0 = t & 31;
        float acc[4] = {0.f, 0.f, 0.f, 0.f};
        #pragma unroll 8
        for (int nn = 0; nn < 128; ++nn) {
            float vv = vl[e0][nn];
            #pragma unroll
            for (int i = 0; i < 4; ++i)
                acc[i] += pl[d0 + 8 * i][nn] * vv;
        }
        #pragma unroll
        for (int i = 0; i < 4; ++i)
            atomicAdd(&ctx[((size_t)bh * 32 + d0 + 8 * i) * 32 + e0], acc[i]);
    } else {
        int bg = bid - 512;              // (b,g)
        const float4* xp = (const float4*)(x + (size_t)bg * 32768);
        float s = 0.f, ss = 0.f;
        #pragma unroll
        for (int j = 0; j < 32; ++j) {
            float4 v = xp[t + 256 * j];
            s  += v.x + v.y + v.z + v.w;
            ss += v.x*v.x + v.y*v.y + v.z*v.z + v.w*v.w;
        }
        #pragma unroll
        for (int off = 32; off > 0; off >>= 1) {
            s  += __shfl_down(s, off, 64);
            ss += __shfl_down(ss, off, 64);
        }
        int wave = t >> 6;
        if ((t & 63) == 0) { pl[0][wave * 2] = s; pl[0][wave * 2 + 1] = ss; }
        __syncthreads();
        if (t == 0) {
            statacc[bg * 2]     = pl[0][0] + pl[0][2] + pl[0][4] + pl[0][6];
            statacc[bg * 2 + 1] = pl[0][1] + pl[0][3] + pl[0][5] + pl[0][7];
        }
    }
}

// ---------------------------------------------------------------------------
// L3: A-fold (no GN here): normalize ctx by rowsum, M = w_out@ctx^T in LDS,
// A16[b,o,c] = bf16(wt), biasb[b,o] = M.b_q + b_out.
__global__ __launch_bounds__(256) void a_kernel(const float* __restrict__ ctx,
                                                const float* __restrict__ rowsum,
                                                const float* __restrict__ w_out,
                                                const float* __restrict__ w_q,
                                                const float* __restrict__ b_q,
                                                const float* __restrict__ b_out,
                                                ushort* __restrict__ A16,
                                                float* __restrict__ biasb) {
    __shared__ float ctxl[4][32][33];
    __shared__ float wol[16][128];
    __shared__ float ml[16][128];
    int b = blockIdx.x >> 4, ot = (blockIdx.x & 15) << 4;
    int t = threadIdx.x;
    #pragma unroll
    for (int j = 0; j < 16; ++j) {
        int e = t + 256 * j;            // 0..4095
        float inv = 1.f / rowsum[b * 128 + (e >> 5)];
        ctxl[e >> 10][(e >> 5) & 31][e & 31] = ctx[(size_t)b * 4096 + e] * inv;
    }
    #pragma unroll
    for (int j = 0; j < 8; ++j) {
        int e = t + 256 * j;            // 0..2047
        wol[e >> 7][e & 127] = w_out[(ot + (e >> 7)) * 128 + (e & 127)];
    }
    __syncthreads();
    #pragma unroll
    for (int j = 0; j < 8; ++j) {
        int e = t + 256 * j;
        int o = e >> 7, hd = e & 127, h = hd >> 5, d = hd & 31;
        float acc = 0.f;
        #pragma unroll
        for (int ee = 0; ee < 32; ++ee) acc += wol[o][h * 32 + ee] * ctxl[h][d][ee];
        ml[o][hd] = acc;
    }
    __syncthreads();
    int c = t;
    float wt[16];
    #pragma unroll
    for (int o = 0; o < 16; ++o) wt[o] = 0.f;
    for (int hd = 0; hd < 128; ++hd) {
        float wq = w_q[hd * 256 + c];
        #pragma unroll
        for (int o = 0; o < 16; ++o) wt[o] += ml[o][hd] * wq;
    }
    ushort* Abp = A16 + ((size_t)b * 256 + ot) * 256 + c;
    #pragma unroll
    for (int o = 0; o < 16; ++o)
        Abp[(size_t)o * 256] = f2bf(wt[o]);
    if (t < 16) {
        int o = t;
        float md = 0.f;
        #pragma unroll 8
        for (int hd = 0; hd < 128; ++hd) md += ml[o][hd] * b_q[hd];
        biasb[(size_t)b * 256 + ot + o] = md + b_out[ot + o];
    }
}

// ---------------------------------------------------------------------------
// L4: out = A16 @ xn^T + bias, xn = GN-affine(x) applied in the B-pack stage.
// BM=256, BN=64, BK=64; 8 waves (4x2); A frags DIRECT from L2 (A16 128 KB/b).
// LDS = 26 KB.
__global__ __launch_bounds__(512) void out_gemm_fused(const ushort* __restrict__ A16,
                                                      const float* __restrict__ x,
                                                      const float* __restrict__ statacc,
                                                      const float* __restrict__ gn_w,
                                                      const float* __restrict__ gn_b,
                                                      const float* __restrict__ biasb,
                                                      float* __restrict__ out) {
    __shared__ ushort lB[64 * 64];      // 8 KB
    __shared__ float scratch[64 * 64];  // 16 KB, granule-swizzled
    __shared__ float sct[256][2];       // 2 KB (sc, tc per channel)
    int b = blockIdx.y;
    int n0 = blockIdx.x * 64;
    int t = threadIdx.x;
    int l = t & 63, wid = t >> 6;
    int wr = wid >> 1, wc = wid & 1;          // 4 x 2 wave grid
    int lr = l & 15, lg = l >> 4;
    const ushort* Ab = A16 + (size_t)b * 65536;
    const float* xb = x + (size_t)b * 256 * 4096 + n0;
    int sp = t & 31, sj4 = t >> 5;            // pack: k-pair 2sp,2sp+1; n-quad (0..15)
    if (t < 256) {
        int g = t >> 3;
        float S  = statacc[(b * 32 + g) * 2];
        float SS = statacc[(b * 32 + g) * 2 + 1];
        float mu  = S * (1.f / 32768.f);
        float var = SS * (1.f / 32768.f) - mu * mu;
        float sc = rsqrtf(var + 1e-5f) * gn_w[t];
        sct[t][0] = sc;
        sct[t][1] = gn_b[t] - mu * sc;
    }
    const ushort* ArA = Ab + (size_t)(wr * 64 + lr) * 256;       // mi=0
    const ushort* ArB = Ab + (size_t)(wr * 64 + 16 + lr) * 256;  // mi=1
    const ushort* ArC = Ab + (size_t)(wr * 64 + 32 + lr) * 256;  // mi=2
    const ushort* ArD = Ab + (size_t)(wr * 64 + 48 + lr) * 256;  // mi=3
    int kq0 = lg * 8, kq1 = (4 + lg) * 8;
    float4 b0_, b1_;
    bf16x8 af0a_, af0b_, af1a_, af1b_, af2a_, af2b_, af3a_, af3b_;
    int rB = t >> 4, gB = t & 15;             // B rows rB, 32+rB; granule of 16
#define OG_LOADB(k0) { \
    b0_ = *(const float4*)&xb[(size_t)((k0) + rB)      * 4096 + gB * 4]; \
    b1_ = *(const float4*)&xb[(size_t)((k0) + 32 + rB) * 4096 + gB * 4]; }
#define OG_LOADAF(k0) { \
    af0a_ = *(const bf16x8*)(ArA + (k0) + kq0); af0b_ = *(const bf16x8*)(ArA + (k0) + kq1); \
    af1a_ = *(const bf16x8*)(ArB + (k0) + kq0); af1b_ = *(const bf16x8*)(ArB + (k0) + kq1); \
    af2a_ = *(const bf16x8*)(ArC + (k0) + kq0); af2b_ = *(const bf16x8*)(ArC + (k0) + kq1); \
    af3a_ = *(const bf16x8*)(ArD + (k0) + kq0); af3b_ = *(const bf16x8*)(ArD + (k0) + kq1); }
    OG_LOADB(0);
    f32x4 acc[4][2] = {};
    for (int it = 0; it < 4; ++it) {
        int k0 = it * 64;
        *(float4*)((char*)scratch + (rB)      * 256 + ((gB ^ (((rB)      >> 1) & 15)) * 16)) = b0_;
        *(float4*)((char*)scratch + (32 + rB) * 256 + ((gB ^ (((32 + rB) >> 1) & 15)) * 16)) = b1_;
        __syncthreads();
        if (it < 3) OG_LOADB(k0 + 64);       // B prefetch
        OG_LOADAF(k0);                       // A frags direct from L2
        {
            int js = sj4 ^ (sp & 15);
            float sc0 = sct[k0 + 2 * sp][0],     tc0 = sct[k0 + 2 * sp][1];
            float sc1 = sct[k0 + 2 * sp + 1][0], tc1 = sct[k0 + 2 * sp + 1][1];
            float4 s0 = *(const float4*)((char*)scratch + (2*sp)   * 256 + js * 16);
            float4 s2 = *(const float4*)((char*)scratch + (2*sp+1) * 256 + js * 16);
            float c0v[4] = {s0.x, s0.y, s0.z, s0.w};
            float c1v[4] = {s2.x, s2.y, s2.z, s2.w};
            #pragma unroll
            for (int w4 = 0; w4 < 4; ++w4) {
                int n = sj4 * 4 + w4;
                unsigned pk = pack2(c0v[w4] * sc0 + tc0, c1v[w4] * sc1 + tc1);
                *(unsigned*)((char*)lB + n * 128 + (((sp >> 2) ^ (n & 7)) * 16) + (sp & 3) * 4) = pk;
            }
        }
        __syncthreads();
        __builtin_amdgcn_s_setprio(1);
        {   // ks = 0
            int br0 = wc * 32 + lr,      q0 = lg ^ (br0 & 7);
            int br1 = wc * 32 + 16 + lr, q1 = lg ^ (br1 & 7);
            bf16x8 bv0 = *(const bf16x8*)((const char*)lB + br0 * 128 + q0 * 16);
            bf16x8 bv1 = *(const bf16x8*)((const char*)lB + br1 * 128 + q1 * 16);
            acc[0][0] = __builtin_amdgcn_mfma_f32_16x16x32_bf16(af0a_, bv0, acc[0][0], 0, 0, 0);
            acc[0][1] = __builtin_amdgcn_mfma_f32_16x16x32_bf16(af0a_, bv1, acc[0][1], 0, 0, 0);
            acc[1][0] = __builtin_amdgcn_mfma_f32_16x16x32_bf16(af1a_, bv0, acc[1][0], 0, 0, 0);
            acc[1][1] = __builtin_amdgcn_mfma_f32_16x16x32_bf16(af1a_, bv1, acc[1][1], 0, 0, 0);
            acc[2][0] = __builtin_amdgcn_mfma_f32_16x16x32_bf16(af2a_, bv0, acc[2][0], 0, 0, 0);
            acc[2][1] = __builtin_amdgcn_mfma_f32_16x16x32_bf16(af2a_, bv1, acc[2][1], 0, 0, 0);
            acc[3][0] = __builtin_amdgcn_mfma_f32_16x16x32_bf16(af3a_, bv0, acc[3][0], 0, 0, 0);
            acc[3][1] = __builtin_amdgcn_mfma_f32_16x16x32_bf16(af3a_, bv1, acc[3][1], 0, 0, 0);
        }
        {   // ks = 1
            int br0 = wc * 32 + lr,      q0 = (4 + lg) ^ (br0 & 7);
            int br1 = wc * 32 + 16 + lr, q1 = (4 + lg) ^ (br1 & 7);
            bf16x8 bv0 = *(const bf16x8*)((const char*)lB + br0 * 128 + q0 * 16);
            bf16x8 bv1 = *(const bf16x8*)((const char*)lB + br1 * 128 + q1 * 16);
            acc[0][0] = __builtin_amdgcn_mfma_f32_16x16x32_bf16(af0b_, bv0, acc[0][0], 0, 0, 0);
            acc[0][1] = __builtin_amdgcn_mfma_f32_16x16x32_bf16(af0b_, bv1, acc[0][1], 0, 0, 0);
            acc[1][0] = __builtin_amdgcn_mfma_f32_16x16x32_bf16(af1b_, bv0, acc[1][0], 0, 0, 0);
            acc[1][1] = __builtin_amdgcn_mfma_f32_16x16x32_bf16(af1b_, bv1, acc[1][1], 0, 0, 0);
            acc[2][0] = __builtin_amdgcn_mfma_f32_16x16x32_bf16(af2b_, bv0, acc[2][0], 0, 0, 0);
            acc[2][1] = __builtin_amdgcn_mfma_f32_16x16x32_bf16(af2b_, bv1, acc[2][1], 0, 0, 0);
            acc[3][0] = __builtin_amdgcn_mfma_f32_16x16x32_bf16(af3b_, bv0, acc[3][0], 0, 0, 0);
            acc[3][1] = __builtin_amdgcn_mfma_f32_16x16x32_bf16(af3b_, bv1, acc[3][1], 0, 0, 0);
        }
        __builtin_amdgcn_s_setprio(0);
        __syncthreads();
    }
#undef OG_LOADB
#undef OG_LOADAF
    const float* bp = biasb + (size_t)b * 256;
    int orow = wr * 64, ocol = n0 + wc * 32 + lr;
    #pragma unroll
    for (int mi = 0; mi < 4; ++mi) {
        int rb2 = orow + mi * 16 + lg * 4;
        float4 b4 = *(const float4*)&bp[rb2];
        float bvr[4] = {b4.x, b4.y, b4.z, b4.w};
        #pragma unroll
        for (int ni = 0; ni < 2; ++ni) {
            int cc = ocol + ni * 16;
            #pragma unroll
            for (int r = 0; r < 4; ++r)
                out[((size_t)b * 256 + rb2 + r) * 4096 + cc] = acc[mi][ni][r] + bvr[r];
        }
    }
}

extern "C" void kernel_launch(void* const* d_in, const int* in_sizes, int n_in,
                              void* d_out, int out_size, void* d_ws, size_t ws_size,
                              hipStream_t stream) {
    const float* x     = (const float*)d_in[0];
    const float* cond  = (const float*)d_in[1];
    const float* gn_w  = (const float*)d_in[2];
    const float* gn_b  = (const float*)d_in[3];
    const float* w_q   = (const float*)d_in[4];
    const float* b_q   = (const float*)d_in[5];
    const float* w_kv  = (const float*)d_in[6];
    const float* b_kv  = (const float*)d_in[7];
    const float* w_out = (const float*)d_in[8];
    const float* b_out = (const float*)d_in[9];
    float* out = (float*)d_out;

    float* f       = (float*)d_ws;
    float* statacc = f;                     // 1024 floats (plain stores)
    float* rowsum  = f + 1024;              // 2048 floats  (zeroed in kv_gemm)
    float* ctx     = f + 3072;              // 65536 floats (zeroed in kv_gemm)
    float* biasb   = f + 68608;             // 4096 floats
    ushort* u      = (ushort*)(f + 72704);
    ushort* kv16   = u;                     // 4194304
    ushort* A16    = u + 4194304;           // 1048576

    // L1: kv GEMM (A direct from L2, 12 KB LDS) + zeroing of rowsum/ctx
    kv_gemm<<<dim3(32, 2, 16), 256, 0, stream>>>(w_kv, cond, b_kv, kv16, rowsum);
    // L2: partial context (atomics) + GN stats, one dispatch
    ctxstats_kernel<<<1024, 256, 0, stream>>>(kv16, x, rowsum, ctx, statacc);
    // L3: fold attention weights into per-batch A16 + bias (GN-free)
    a_kernel<<<256, 256, 0, stream>>>(ctx, rowsum, w_out, w_q, b_q, b_out, A16, biasb);
    // L4: out = A @ GN(x)^T + bias (A direct from L2, 26 KB LDS)
    out_gemm_fused<<<dim3(64, 16), 512, 0, stream>>>(A16, x, statacc, gn_w, gn_b, biasb, out);
}

// Round 21
// 78.290 us; speedup vs baseline: 1.4173x; 1.4173x over previous
//
#include <hip/hip_runtime.h>
#include <hip/hip_bf16.h>

typedef __attribute__((ext_vector_type(8))) short bf16x8;
typedef __attribute__((ext_vector_type(4))) float f32x4;

__device__ __forceinline__ ushort f2bf(float f) {
    __hip_bfloat16 h = __float2bfloat16(f);
    return __builtin_bit_cast(ushort, h);
}
__device__ __forceinline__ unsigned pack2(float a, float b) {
    return (unsigned)f2bf(a) | ((unsigned)f2bf(b) << 16);
}
__device__ __forceinline__ float bflo(unsigned u) { return __uint_as_float(u << 16); }
__device__ __forceinline__ float bfhi(unsigned u) { return __uint_as_float(u & 0xffff0000u); }

__device__ __forceinline__ void unpack8(uint4 r, float* o) {
    o[0] = bflo(r.x); o[1] = bfhi(r.x); o[2] = bflo(r.y); o[3] = bfhi(r.y);
    o[4] = bflo(r.z); o[5] = bfhi(r.z); o[6] = bflo(r.w); o[7] = bfhi(r.w);
}

// ---------------------------------------------------------------------------
// L1: kv16 = bf16(w_kv @ cond + b_kv). BM=128, BN=32, BK=64, K=512.
// 256 thr (4 waves), 28 KB LDS. grid (32 nc, 2 rb, 16 b).
// First 264 flat-blocks also zero rowsum+ctx (consumed next dispatch).
__global__ __launch_bounds__(256) void kv_gemm(const float* __restrict__ w_kv,
                                               const float* __restrict__ cond,
                                               const float* __restrict__ b_kv,
                                               ushort* __restrict__ kv16,
                                               float* __restrict__ zbase) {
    __shared__ ushort lA[128 * 64];     // 16 KB
    __shared__ ushort lB[32 * 64];      // 4 KB
    __shared__ float scratch[64 * 32];  // 8 KB, granule-swizzled
    int nc = blockIdx.x, rb = blockIdx.y, b = blockIdx.z;
    int t = threadIdx.x;
    int fid = blockIdx.x + 32 * (blockIdx.y + 2 * blockIdx.z);
    if (fid < 264) zbase[fid * 256 + t] = 0.f;   // rowsum(2048)+ctx(65536)
    int col0 = nc * 32, row0 = rb * 128;
    int l = t & 63, w = t >> 6;          // 4 waves, rows w*32..w*32+31
    int lr = l & 15, lg = l >> 4;
    const float* Ab32 = w_kv + (size_t)row0 * 512;
    const float* Bb = cond + (size_t)b * 512 * 1024 + col0;
    int rA = t >> 3, gAr = t & 7, gw = gAr ^ (rA & 7);  // (32j+rA)&7==rA&7
    int rB = t >> 3, gB = t & 7;         // rows rB, 32+rB; granule gB of 8
    int sp = t & 31, sj4 = (t >> 5) & 7; // pack: rows 2sp,2sp+1; n-quad sj4
    float4 ka0_, ka1_, ka2_, ka3_, ka4_, ka5_, ka6_, ka7_;
    float4 kb0_, kb1_;
#define KG_LOADA(k0) { \
    ka0_ = *(const float4*)&Ab32[(size_t)(rA)      * 512 + (k0) + gAr * 8]; \
    ka1_ = *(const float4*)&Ab32[(size_t)(rA)      * 512 + (k0) + gAr * 8 + 4]; \
    ka2_ = *(const float4*)&Ab32[(size_t)(32 + rA) * 512 + (k0) + gAr * 8]; \
    ka3_ = *(const float4*)&Ab32[(size_t)(32 + rA) * 512 + (k0) + gAr * 8 + 4]; \
    ka4_ = *(const float4*)&Ab32[(size_t)(64 + rA) * 512 + (k0) + gAr * 8]; \
    ka5_ = *(const float4*)&Ab32[(size_t)(64 + rA) * 512 + (k0) + gAr * 8 + 4]; \
    ka6_ = *(const float4*)&Ab32[(size_t)(96 + rA) * 512 + (k0) + gAr * 8]; \
    ka7_ = *(const float4*)&Ab32[(size_t)(96 + rA) * 512 + (k0) + gAr * 8 + 4]; }
#define KG_LOADB(k0) { \
    kb0_ = *(const float4*)&Bb[(size_t)((k0) + rB)      * 1024 + gB * 4]; \
    kb1_ = *(const float4*)&Bb[(size_t)((k0) + 32 + rB) * 1024 + gB * 4]; }
#define KG_WRITEA() { uint4 p; \
    p.x = pack2(ka0_.x, ka0_.y); p.y = pack2(ka0_.z, ka0_.w); \
    p.z = pack2(ka1_.x, ka1_.y); p.w = pack2(ka1_.z, ka1_.w); \
    *(uint4*)((char*)lA + (size_t)((rA)      * 8 + gw) * 16) = p; \
    p.x = pack2(ka2_.x, ka2_.y); p.y = pack2(ka2_.z, ka2_.w); \
    p.z = pack2(ka3_.x, ka3_.y); p.w = pack2(ka3_.z, ka3_.w); \
    *(uint4*)((char*)lA + (size_t)((32 + rA) * 8 + gw) * 16) = p; \
    p.x = pack2(ka4_.x, ka4_.y); p.y = pack2(ka4_.z, ka4_.w); \
    p.z = pack2(ka5_.x, ka5_.y); p.w = pack2(ka5_.z, ka5_.w); \
    *(uint4*)((char*)lA + (size_t)((64 + rA) * 8 + gw) * 16) = p; \
    p.x = pack2(ka6_.x, ka6_.y); p.y = pack2(ka6_.z, ka6_.w); \
    p.z = pack2(ka7_.x, ka7_.y); p.w = pack2(ka7_.z, ka7_.w); \
    *(uint4*)((char*)lA + (size_t)((96 + rA) * 8 + gw) * 16) = p; }
#define KG_WRITEB() { \
    *(float4*)((char*)scratch + (rB)      * 128 + ((gB ^ (((rB)      >> 1) & 7)) * 16)) = kb0_; \
    *(float4*)((char*)scratch + (32 + rB) * 128 + ((gB ^ (((32 + rB) >> 1) & 7)) * 16)) = kb1_; }
#define KG_PACKB() { \
    int js = sj4 ^ (sp & 7); \
    float4 s0 = *(const float4*)((char*)scratch + (2*sp)   * 128 + js * 16); \
    float4 s2 = *(const float4*)((char*)scratch + (2*sp+1) * 128 + js * 16); \
    float c0v[4] = {s0.x, s0.y, s0.z, s0.w}; \
    float c1v[4] = {s2.x, s2.y, s2.z, s2.w}; \
    _Pragma("unroll") \
    for (int w4 = 0; w4 < 4; ++w4) { \
        int n = sj4 * 4 + w4; \
        unsigned pk = pack2(c0v[w4], c1v[w4]); \
        *(unsigned*)((char*)lB + n * 128 + (((sp >> 2) ^ (n & 7)) * 16) + (sp & 3) * 4) = pk; \
    } }
    KG_LOADA(0); KG_LOADB(0);
    f32x4 acc[2][2] = {};
    for (int it = 0; it < 8; ++it) {
        KG_WRITEA();
        KG_WRITEB();
        __syncthreads();
        if (it < 7) { KG_LOADA(it * 64 + 64); KG_LOADB(it * 64 + 64); }  // prefetch
        KG_PACKB();
        __syncthreads();
        __builtin_amdgcn_s_setprio(1);
        #pragma unroll
        for (int ks = 0; ks < 2; ++ks) {
            bf16x8 av[2], bv[2];
            #pragma unroll
            for (int mi = 0; mi < 2; ++mi) {
                int ar = w * 32 + mi * 16 + lr;
                int q = (ks * 4 + lg) ^ (ar & 7);
                av[mi] = *(const bf16x8*)((const char*)lA + ar * 128 + q * 16);
            }
            #pragma unroll
            for (int ni = 0; ni < 2; ++ni) {
                int br = ni * 16 + lr;
                int q = (ks * 4 + lg) ^ (br & 7);
                bv[ni] = *(const bf16x8*)((const char*)lB + br * 128 + q * 16);
            }
            #pragma unroll
            for (int mi = 0; mi < 2; ++mi)
                #pragma unroll
                for (int ni = 0; ni < 2; ++ni)
                    acc[mi][ni] = __builtin_amdgcn_mfma_f32_16x16x32_bf16(
                        av[mi], bv[ni], acc[mi][ni], 0, 0, 0);
        }
        __builtin_amdgcn_s_setprio(0);
        __syncthreads();
    }
#undef KG_LOADA
#undef KG_LOADB
#undef KG_WRITEA
#undef KG_WRITEB
#undef KG_PACKB
    int orow = row0 + w * 32;
    #pragma unroll
    for (int mi = 0; mi < 2; ++mi) {
        int rbase = orow + mi * 16 + lg * 4;
        float4 b4 = *(const float4*)&b_kv[rbase];
        float bvr[4] = {b4.x, b4.y, b4.z, b4.w};
        #pragma unroll
        for (int ni = 0; ni < 2; ++ni) {
            int cc = col0 + ni * 16 + lr;
            #pragma unroll
            for (int r = 0; r < 4; ++r)
                kv16[((size_t)b * 256 + rbase + r) * 1024 + cc] = f2bf(acc[mi][ni][r] + bvr[r]);
        }
    }
}

// ---------------------------------------------------------------------------
// L2 mixed: bid<512: partial context (UNNORMALIZED, atomics):
//   ctx[d,e] += sum_n exp(k[d,n]) v[e,n], rowsum[d] += sum_n exp(k[d,n]).
//   bid>=512: GroupNorm sums for x, one block per (b,g), plain store.
__global__ __launch_bounds__(256) void ctxstats_kernel(const ushort* __restrict__ kv,
                                                       const float* __restrict__ x,
                                                       float* __restrict__ rowsum,
                                                       float* __restrict__ ctx,
                                                       float* __restrict__ statacc) {
    __shared__ float pl[32][129], vl[32][129];
    int bid = blockIdx.x, t = threadIdx.x;
    if (bid < 512) {
        int bh = bid >> 3, b = bh >> 2, h = bh & 3;
        int n0 = (bid & 7) * 128;
        int r = t >> 3, cs = (t & 7) * 16;
        const ushort* kp = kv + ((size_t)b * 256 + h * 32 + r) * 1024 + n0 + cs;
        const ushort* vp = kv + ((size_t)b * 256 + 128 + h * 32 + r) * 1024 + n0 + cs;
        float kvals[16], vvals[16];
        unpack8(((const uint4*)kp)[0], kvals);
        unpack8(((const uint4*)kp)[1], kvals + 8);
        unpack8(((const uint4*)vp)[0], vvals);
        unpack8(((const uint4*)vp)[1], vvals + 8);
        float psum = 0.f;
        #pragma unroll
        for (int i = 0; i < 16; ++i) {
            float e = __expf(kvals[i]);
            pl[r][cs + i] = e;
            vl[r][cs + i] = vvals[i];
            psum += e;
        }
        psum += __shfl_xor(psum, 1, 64);
        psum += __shfl_xor(psum, 2, 64);
        psum += __shfl_xor(psum, 4, 64);
        if ((t & 7) == 0) atomicAdd(&rowsum[bh * 32 + r], psum);
        __syncthreads();
        int d0 = t >> 5, e0 = t & 31;
        float acc[4] = {0.f, 0.f, 0.f, 0.f};
        #pragma unroll 8
        for (int nn = 0; nn < 128; ++nn) {
            float vv = vl[e0][nn];
            #pragma unroll
            for (int i = 0; i < 4; ++i)
                acc[i] += pl[d0 + 8 * i][nn] * vv;
        }
        #pragma unroll
        for (int i = 0; i < 4; ++i)
            atomicAdd(&ctx[((size_t)bh * 32 + d0 + 8 * i) * 32 + e0], acc[i]);
    } else {
        int bg = bid - 512;              // (b,g)
        const float4* xp = (const float4*)(x + (size_t)bg * 32768);
        float s = 0.f, ss = 0.f;
        #pragma unroll
        for (int j = 0; j < 32; ++j) {
            float4 v = xp[t + 256 * j];
            s  += v.x + v.y + v.z + v.w;
            ss += v.x*v.x + v.y*v.y + v.z*v.z + v.w*v.w;
        }
        #pragma unroll
        for (int off = 32; off > 0; off >>= 1) {
            s  += __shfl_down(s, off, 64);
            ss += __shfl_down(ss, off, 64);
        }
        int wave = t >> 6;
        if ((t & 63) == 0) { pl[0][wave * 2] = s; pl[0][wave * 2 + 1] = ss; }
        __syncthreads();
        if (t == 0) {
            statacc[bg * 2]     = pl[0][0] + pl[0][2] + pl[0][4] + pl[0][6];
            statacc[bg * 2 + 1] = pl[0][1] + pl[0][3] + pl[0][5] + pl[0][7];
        }
    }
}

// ---------------------------------------------------------------------------
// L3: A-fold (no GN here): normalize ctx by rowsum, M = w_out@ctx^T in LDS,
// A16[b,o,c] = bf16(wt), biasb[b,o] = M.b_q + b_out.
__global__ __launch_bounds__(256) void a_kernel(const float* __restrict__ ctx,
                                                const float* __restrict__ rowsum,
                                                const float* __restrict__ w_out,
                                                const float* __restrict__ w_q,
                                                const float* __restrict__ b_q,
                                                const float* __restrict__ b_out,
                                                ushort* __restrict__ A16,
                                                float* __restrict__ biasb) {
    __shared__ float ctxl[4][32][33];
    __shared__ float wol[16][128];
    __shared__ float ml[16][128];
    int b = blockIdx.x >> 4, ot = (blockIdx.x & 15) << 4;
    int t = threadIdx.x;
    #pragma unroll
    for (int j = 0; j < 16; ++j) {
        int e = t + 256 * j;            // 0..4095
        float inv = 1.f / rowsum[b * 128 + (e >> 5)];
        ctxl[e >> 10][(e >> 5) & 31][e & 31] = ctx[(size_t)b * 4096 + e] * inv;
    }
    #pragma unroll
    for (int j = 0; j < 8; ++j) {
        int e = t + 256 * j;            // 0..2047
        wol[e >> 7][e & 127] = w_out[(ot + (e >> 7)) * 128 + (e & 127)];
    }
    __syncthreads();
    #pragma unroll
    for (int j = 0; j < 8; ++j) {
        int e = t + 256 * j;
        int o = e >> 7, hd = e & 127, h = hd >> 5, d = hd & 31;
        float acc = 0.f;
        #pragma unroll
        for (int ee = 0; ee < 32; ++ee) acc += wol[o][h * 32 + ee] * ctxl[h][d][ee];
        ml[o][hd] = acc;
    }
    __syncthreads();
    int c = t;
    float wt[16];
    #pragma unroll
    for (int o = 0; o < 16; ++o) wt[o] = 0.f;
    for (int hd = 0; hd < 128; ++hd) {
        float wq = w_q[hd * 256 + c];
        #pragma unroll
        for (int o = 0; o < 16; ++o) wt[o] += ml[o][hd] * wq;
    }
    ushort* Abp = A16 + ((size_t)b * 256 + ot) * 256 + c;
    #pragma unroll
    for (int o = 0; o < 16; ++o)
        Abp[(size_t)o * 256] = f2bf(wt[o]);
    if (t < 16) {
        int o = t;
        float md = 0.f;
        #pragma unroll 8
        for (int hd = 0; hd < 128; ++hd) md += ml[o][hd] * b_q[hd];
        biasb[(size_t)b * 256 + ot + o] = md + b_out[ot + o];
    }
}

// ---------------------------------------------------------------------------
// L4: out = A16 @ xn^T + bias, xn = GN-affine(x) applied in the B-pack stage.
// BM=256, BN=64, BK=64; 8 waves (4x2); staged A; 2-deep B prefetch; 58 KB LDS.
__global__ __launch_bounds__(512) void out_gemm_fused(const ushort* __restrict__ A16,
                                                      const float* __restrict__ x,
                                                      const float* __restrict__ statacc,
                                                      const float* __restrict__ gn_w,
                                                      const float* __restrict__ gn_b,
                                                      const float* __restrict__ biasb,
                                                      float* __restrict__ out) {
    __shared__ ushort lA[256 * 64];     // 32 KB
    __shared__ ushort lB[64 * 64];      // 8 KB
    __shared__ float scratch[64 * 64];  // 16 KB, granule-swizzled
    __shared__ float sct[256][2];       // 2 KB (sc, tc per channel)
    int b = blockIdx.y;
    int n0 = blockIdx.x * 64;
    int t = threadIdx.x;
    int l = t & 63, wid = t >> 6;
    int wr = wid >> 1, wc = wid & 1;          // 4 x 2 wave grid
    int lr = l & 15, lg = l >> 4;
    const ushort* Ab = A16 + (size_t)b * 65536;
    const float* xb = x + (size_t)b * 256 * 4096 + n0;
    int sp = t & 31, sj4 = t >> 5;            // pack: k-pair 2sp,2sp+1; n-quad (0..15)
    if (t < 256) {
        int g = t >> 3;
        float S  = statacc[(b * 32 + g) * 2];
        float SS = statacc[(b * 32 + g) * 2 + 1];
        float mu  = S * (1.f / 32768.f);
        float var = SS * (1.f / 32768.f) - mu * mu;
        float sc = rsqrtf(var + 1e-5f) * gn_w[t];
        sct[t][0] = sc;
        sct[t][1] = gn_b[t] - mu * sc;
    }
    uint4 a0_, a1_, a2_, a3_;
    float4 b0_, b1_;        // B set 0
    float4 c0_, c1_;        // B set 1 (2-deep prefetch)
    int rA = t >> 3, gA = (t & 7) ^ (rA & 7); // (64k+rA)&7 == rA&7
    int rB = t >> 4, gB = t & 15;             // B rows rB, 32+rB; granule of 16
#define OG_LOADA(k0) { \
    a0_ = *(const uint4*)(Ab + (size_t)(rA)       * 256 + (k0) + gA * 8); \
    a1_ = *(const uint4*)(Ab + (size_t)(64 + rA)  * 256 + (k0) + gA * 8); \
    a2_ = *(const uint4*)(Ab + (size_t)(128 + rA) * 256 + (k0) + gA * 8); \
    a3_ = *(const uint4*)(Ab + (size_t)(192 + rA) * 256 + (k0) + gA * 8); }
#define OG_LOADB0(k0) { \
    b0_ = *(const float4*)&xb[(size_t)((k0) + rB)      * 4096 + gB * 4]; \
    b1_ = *(const float4*)&xb[(size_t)((k0) + 32 + rB) * 4096 + gB * 4]; }
#define OG_LOADB1(k0) { \
    c0_ = *(const float4*)&xb[(size_t)((k0) + rB)      * 4096 + gB * 4]; \
    c1_ = *(const float4*)&xb[(size_t)((k0) + 32 + rB) * 4096 + gB * 4]; }
#define OG_WRITEB(v0, v1) { \
    *(float4*)((char*)scratch + (rB)      * 256 + ((gB ^ (((rB)      >> 1) & 15)) * 16)) = v0; \
    *(float4*)((char*)scratch + (32 + rB) * 256 + ((gB ^ (((32 + rB) >> 1) & 15)) * 16)) = v1; }
    OG_LOADA(0); OG_LOADB0(0); 
    f32x4 acc[4][2] = {};
    for (int it = 0; it < 4; ++it) {
        int k0 = it * 64;
        *(uint4*)((char*)lA + (size_t)t * 16)          = a0_;
        *(uint4*)((char*)lA + (size_t)(512 + t) * 16)  = a1_;
        *(uint4*)((char*)lA + (size_t)(1024 + t) * 16) = a2_;
        *(uint4*)((char*)lA + (size_t)(1536 + t) * 16) = a3_;
        if (it & 1) { OG_WRITEB(c0_, c1_); } else { OG_WRITEB(b0_, b1_); }
        __syncthreads();
        if (it < 3) OG_LOADA(k0 + 64);
        if (it == 0) OG_LOADB1(64);          // fill 2nd slot early
        if (it == 1 && 1) OG_LOADB0(128);    // refill set0 (2-deep)
        if (it == 2) OG_LOADB1(192);         // refill set1
        {
            int js = sj4 ^ (sp & 15);
            float sc0 = sct[k0 + 2 * sp][0],     tc0 = sct[k0 + 2 * sp][1];
            float sc1 = sct[k0 + 2 * sp + 1][0], tc1 = sct[k0 + 2 * sp + 1][1];
            float4 s0 = *(const float4*)((char*)scratch + (2*sp)   * 256 + js * 16);
            float4 s2 = *(const float4*)((char*)scratch + (2*sp+1) * 256 + js * 16);
            float c0v[4] = {s0.x, s0.y, s0.z, s0.w};
            float c1v[4] = {s2.x, s2.y, s2.z, s2.w};
            #pragma unroll
            for (int w4 = 0; w4 < 4; ++w4) {
                int n = sj4 * 4 + w4;
                unsigned pk = pack2(c0v[w4] * sc0 + tc0, c1v[w4] * sc1 + tc1);
                *(unsigned*)((char*)lB + n * 128 + (((sp >> 2) ^ (n & 7)) * 16) + (sp & 3) * 4) = pk;
            }
        }
        __syncthreads();
        __builtin_amdgcn_s_setprio(1);
        #pragma unroll
        for (int ks = 0; ks < 2; ++ks) {
            bf16x8 av[4], bv[2];
            #pragma unroll
            for (int mi = 0; mi < 4; ++mi) {
                int ar = wr * 64 + mi * 16 + lr;
                int q = (ks * 4 + lg) ^ (ar & 7);
                av[mi] = *(const bf16x8*)((const char*)lA + ar * 128 + q * 16);
            }
            #pragma unroll
            for (int ni = 0; ni < 2; ++ni) {
                int br = wc * 32 + ni * 16 + lr;
                int q = (ks * 4 + lg) ^ (br & 7);
                bv[ni] = *(const bf16x8*)((const char*)lB + br * 128 + q * 16);
            }
            #pragma unroll
            for (int mi = 0; mi < 4; ++mi)
                #pragma unroll
                for (int ni = 0; ni < 2; ++ni)
                    acc[mi][ni] = __builtin_amdgcn_mfma_f32_16x16x32_bf16(
                        av[mi], bv[ni], acc[mi][ni], 0, 0, 0);
        }
        __builtin_amdgcn_s_setprio(0);
        __syncthreads();
    }
#undef OG_LOADA
#undef OG_LOADB0
#undef OG_LOADB1
#undef OG_WRITEB
    const float* bp = biasb + (size_t)b * 256;
    int orow = wr * 64, ocol = n0 + wc * 32 + lr;
    #pragma unroll
    for (int mi = 0; mi < 4; ++mi) {
        int rb2 = orow + mi * 16 + lg * 4;
        float4 b4 = *(const float4*)&bp[rb2];
        float bvr[4] = {b4.x, b4.y, b4.z, b4.w};
        #pragma unroll
        for (int ni = 0; ni < 2; ++ni) {
            int cc = ocol + ni * 16;
            #pragma unroll
            for (int r = 0; r < 4; ++r)
                out[((size_t)b * 256 + rb2 + r) * 4096 + cc] = acc[mi][ni][r] + bvr[r];
        }
    }
}

extern "C" void kernel_launch(void* const* d_in, const int* in_sizes, int n_in,
                              void* d_out, int out_size, void* d_ws, size_t ws_size,
                              hipStream_t stream) {
    const float* x     = (const float*)d_in[0];
    const float* cond  = (const float*)d_in[1];
    const float* gn_w  = (const float*)d_in[2];
    const float* gn_b  = (const float*)d_in[3];
    const float* w_q   = (const float*)d_in[4];
    const float* b_q   = (const float*)d_in[5];
    const float* w_kv  = (const float*)d_in[6];
    const float* b_kv  = (const float*)d_in[7];
    const float* w_out = (const float*)d_in[8];
    const float* b_out = (const float*)d_in[9];
    float* out = (float*)d_out;

    float* f       = (float*)d_ws;
    float* statacc = f;                     // 1024 floats (plain stores)
    float* rowsum  = f + 1024;              // 2048 floats  (zeroed in kv_gemm)
    float* ctx     = f + 3072;              // 65536 floats (zeroed in kv_gemm)
    float* biasb   = f + 68608;             // 4096 floats
    ushort* u      = (ushort*)(f + 72704);
    ushort* kv16   = u;                     // 4194304
    ushort* A16    = u + 4194304;           // 1048576

    // L1: kv GEMM (staged A, 28 KB LDS) + zeroing of rowsum/ctx
    kv_gemm<<<dim3(32, 2, 16), 256, 0, stream>>>(w_kv, cond, b_kv, kv16, rowsum);
    // L2: partial context (atomics) + GN stats, one dispatch
    ctxstats_kernel<<<1024, 256, 0, stream>>>(kv16, x, rowsum, ctx, statacc);
    // L3: fold attention weights into per-batch A16 + bias (GN-free)
    a_kernel<<<256, 256, 0, stream>>>(ctx, rowsum, w_out, w_q, b_q, b_out, A16, biasb);
    // L4: out = A @ GN(x)^T + bias (staged A, 2-deep B prefetch)
    out_gemm_fused<<<dim3(64, 16), 512, 0, stream>>>(A16, x, statacc, gn_w, gn_b, biasb, out);
}